// Round 12
// baseline (468.827 us; speedup 1.0000x reference)
//
#include <hip/hip_runtime.h>

#define N_NODES 20000
#define NPAIRS  10000
#define N_EDGES 320000
#define CAP     64
#define KN      15

typedef _Float16 half_t;
typedef _Float16 half2_t __attribute__((ext_vector_type(2)));

// params float-index layout
#define P_ALPHA 0
#define P_BETA  1
#define P_IEPS2 2
#define P_EPS   3
#define P_HC2   16
#define P_RSC2  216
#define P_F1    316

// workspace byte offsets
#define OFF_CNT    0u
#define OFF_COUNTS 80000u
#define OFF_STATS  160000u        // 65 doubles (520 B)
#define OFF_FLAG   160520u        // last-block-done counter (zeroed by memset)
#define OFF_NBC    160528u
#define OFF_NEIGH  240528u
#define OFF_XH     1440528u       // x_h (2.56 MB) aliases buf region: buf is
#define OFF_S2X    4000528u       //   consumed by k_select BEFORE k_stats writes
#define OFF_BUF    1440528u       //   xh/s2xh
#define OFF_PARAMS 6560528u

// tf_l per-template stride (halfs): dword stride 324 = 4 (mod 32)
#define TF_STRIDE 648

// ---- 16-lane reduction via DPP row_ror adds: pure VALU ----
template<int CTRL>
__device__ __forceinline__ float dpp_add(float v) {
  int s = __builtin_bit_cast(int, v);
  int r = __builtin_amdgcn_update_dpp(0, s, CTRL, 0xF, 0xF, true);
  return v + __builtin_bit_cast(float, r);
}
__device__ __forceinline__ float sum16(float v) {
  v = dpp_add<0x128>(v);   // row_ror:8
  v = dpp_add<0x124>(v);   // row_ror:4
  v = dpp_add<0x122>(v);   // row_ror:2
  v = dpp_add<0x121>(v);   // row_ror:1
  return v;
}
// ds_swizzle imm BitMode 0x010: new_lane = lane&0x10 -> broadcast k=0 of group
__device__ __forceinline__ float bcast16(float v) {
  return __builtin_bit_cast(float,
      __builtin_amdgcn_ds_swizzle(__builtin_bit_cast(int, v), 0x010));
}
__device__ __forceinline__ float fdot2(half2_t a, half2_t b, float c) {
  return __builtin_amdgcn_fdot2(a, b, c, false);
}
// force a wave-uniform float into an SGPR (all lanes hold the same value)
__device__ __forceinline__ float sgpr(float v) {
  return __builtin_bit_cast(float,
      __builtin_amdgcn_readfirstlane(__builtin_bit_cast(int, v)));
}

// ---------------- kernel 1: scatter edge ids per source node ----------------
__global__ void k_scatter(const int* __restrict__ ei, int* __restrict__ cnt,
                          int* __restrict__ buf) {
  int e = blockIdx.x * blockDim.x + threadIdx.x;
  if (e >= N_EDGES) return;
  int s = ei[e];
  int slot = atomicAdd(&cnt[s], 1);
  if (slot < CAP) buf[s * CAP + slot] = e;
}

// ---- kernel 2: wave-per-node; select 15 smallest edge ids via ballot-rank --
__global__ void k_select(const int* __restrict__ ei, const int* __restrict__ cnt,
                         const int* __restrict__ buf, int* __restrict__ nbc_g,
                         int* __restrict__ neigh, int* __restrict__ counts) {
  int w = (blockIdx.x * blockDim.x + threadIdx.x) >> 6;   // node
  int lane = threadIdx.x & 63;
  if (w >= N_NODES) return;
  const int* dst = ei + N_EDGES;
  int c = cnt[w];
  int cc = c < CAP ? c : CAP;
  int e = (lane < cc) ? buf[w * CAP + lane] : 0x7fffffff;
  int nb = c < KN ? c : KN;
  bool sel;
  if (cc <= KN) {
    sel = lane < cc;
  } else {
    int rank = 0;
    for (int j = 0; j < cc; j++) {      // cc is wave-uniform
      int ej = __shfl(e, j);
      rank += (ej < e) ? 1 : 0;
    }
    sel = (e != 0x7fffffff) && (rank < KN);
  }
  unsigned long long mask = __ballot(sel);
  if (sel) {
    int pos = __popcll(mask & ((1ull << lane) - 1ull));
    int d = dst[e];
    neigh[w * KN + pos] = d;
    atomicAdd(&counts[d], 1);
  }
  if (lane == 0) {
    nbc_g[w] = nb;
    atomicAdd(&counts[w], 1);
    if (nb < KN) atomicAdd(&counts[0], KN - nb);
  }
}

// ---- kernel 3: x->f16 + ||x~||^2 + weighted sums + last-block finalize -----
#define STATS_BLOCKS 512
__global__ void k_stats(const float* __restrict__ x, const int* __restrict__ counts,
                        double* __restrict__ stats, int* __restrict__ flag,
                        half_t* __restrict__ xh, float* __restrict__ s2xh,
                        const float* __restrict__ tf, const float* __restrict__ c2,
                        const float* __restrict__ alpha0, float* __restrict__ params) {
  int lane = threadIdx.x & 63;
  int wid = threadIdx.x >> 6;
  int gw = blockIdx.x * 4 + wid;
  float accx = 0.f, acc2 = 0.f;
  for (int u = gw; u < N_NODES; u += STATS_BLOCKS * 4) {
    float w = (float)counts[u];
    float val = x[u * 64 + lane];
    half_t h = (half_t)val;
    xh[u * 64 + lane] = h;
    float hv = (float)h;
    float sq = hv * hv;
#pragma unroll
    for (int off = 32; off > 0; off >>= 1) sq += __shfl_xor(sq, off, 64);
    if (lane == 0) s2xh[u] = sq;
    accx += w * val;
    acc2 += w * val * val;
  }
#pragma unroll
  for (int off = 32; off > 0; off >>= 1) acc2 += __shfl_xor(acc2, off, 64);
  __shared__ float redx[4][64];
  __shared__ float red2[4];
  __shared__ int lastsh;
  redx[wid][lane] = accx;
  if (lane == 0) red2[wid] = acc2;
  __syncthreads();
  if (threadIdx.x < 64) {
    float s = redx[0][threadIdx.x] + redx[1][threadIdx.x] +
              redx[2][threadIdx.x] + redx[3][threadIdx.x];
    atomicAdd(&stats[1 + threadIdx.x], (double)s);
  }
  if (threadIdx.x == 0)
    atomicAdd(&stats[0], (double)(red2[0] + red2[1] + red2[2] + red2[3]));
  __syncthreads();
  if (threadIdx.x == 0) {
    __threadfence();
    int old = atomicAdd(flag, 1);
    lastsh = (old == STATS_BLOCKS - 1) ? 1 : 0;
  }
  __syncthreads();
  if (!lastsh) return;
  __threadfence();   // acquire: all blocks' stats atomics are visible
  // ------- finalize (runs once, in the last-finishing block) -------
  __shared__ float sh[4];
  int tid = threadIdx.x;
  if (tid < 64) {
    float s = 0.f, s2 = 0.f;
    for (int tm = 0; tm < 100; tm++) { float v = tf[tm * 64 + tid]; s += v; s2 += v * v; }
    double inv16N = 1.0 / (double)(N_NODES * 16);
    double cross = (stats[1 + tid] * inv16N) * ((double)s / 100.0);
    double B = (double)s2 / 100.0;
    double term = B - 2.0 * cross;
#pragma unroll
    for (int off = 32; off > 0; off >>= 1) term += __shfl_xor(term, off, 64);
    if (tid == 0) {
      double A = stats[0] * inv16N;
      double meanM = A + term;
      float eps = (float)(0.05 * meanM) + 1e-6f;
      float a0 = alpha0[0];
      float alpha = 1.f / (1.f + expf(-a0));
      params[P_ALPHA] = alpha;
      params[P_BETA]  = 1.f - alpha;
      params[P_IEPS2] = 1.4426950408889634f / eps;
      params[P_EPS]   = eps;
      sh[0] = alpha; sh[1] = 1.f - alpha; sh[2] = 1.4426950408889634f / eps;
    }
  }
  __syncthreads();
  if (tid < 100) {
    float alpha = sh[0], beta = sh[1], ieps2 = sh[2];
    int t = tid / 10, mm = tid % 10;
    float h = 0.f;
    for (int r = 0; r < 10; r++) { float cv = c2[t * 100 + mm * 10 + r]; h += cv * cv; }
    float hc2v = 0.1f * h;
    params[P_HC2 + tid] = hc2v;
    float s2 = 0.f;
    for (int f = 0; f < 64; f++) { float v = tf[tid * 64 + f]; s2 += v * v; }
    float rs = 0.f;
    for (int m2 = 0; m2 < 10; m2++) rs += c2[t * 100 + mm * 10 + m2];
    params[P_RSC2 + tid] = rs;
    params[P_F1 + tid] = (beta * s2 + 2.0f * alpha * hc2v) * (-ieps2);
  }
}

// --------- kernel 4: single-pair fused f16-M + drift-folded Sinkhorn --------
// lane = (node_s, t, k). Uniform params forced into SGPRs via readfirstlane;
// c2 rows in LDS. Goal: natural VGPR <= 64 (8-wave tier) with zero spill.
__global__ void __launch_bounds__(320, 4)
k_main(const half_t* __restrict__ xh, const float* __restrict__ tf_g,
       const float* __restrict__ c2_g, const int* __restrict__ nbc_g,
       const int* __restrict__ neigh_g, const float* __restrict__ params,
       const float* __restrict__ s2x_g, float* __restrict__ out) {
  __shared__ __align__(16) half_t tf_l[10 * TF_STRIDE];   // 12.96 KB
  __shared__ __align__(16) float c2_l[1000];              // 4 KB
  __shared__ __align__(16) float hc2_l[100];
  __shared__ __align__(16) float rsc2_l[100];
  __shared__ __align__(16) float F1_l[100];
  __shared__ __align__(16) float bsb_l[20][10][2];        // total ~19.8 KB

  const int tid = threadIdx.x;
  const int node_s = tid / 160;
  const int s = tid % 160;
  const int t = s >> 4;
  const int k = s & 15;
  const bool k0 = (k == 0);
  const int grp = node_s * 10 + t;

  for (int i = tid; i < 6400; i += 320) {
    int tt = i / 640, rem = i - tt * 640;
    tf_l[tt * TF_STRIDE + rem] = (half_t)tf_g[i];
  }
  for (int i = tid; i < 1000; i += 320) c2_l[i] = c2_g[i];
  if (tid < 100) {
    hc2_l[tid]  = params[P_HC2 + tid];
    rsc2_l[tid] = params[P_RSC2 + tid];
    F1_l[tid]   = params[P_F1 + tid];
  }

  // wave-uniform constants -> SGPRs (every lane reads the same address)
  const float alpha = sgpr(params[P_ALPHA]);
  const float beta  = sgpr(params[P_BETA]);
  const float ieps2 = sgpr(params[P_IEPS2]);
  const float eps   = sgpr(params[P_EPS]);
  const float niep  = -ieps2;
  const float twoal = 2.0f * alpha;
  const float ctv10 = 0.2f * twoal * ieps2;    // = ctv*0.1 (drift-compensated)
  const float cab   = 2.0f * beta * ieps2;
  const float c_a2d = -eps * 0.69314718056f;   // Ab -> (beta*M + 2a*cc)
  const float twoal01 = 0.1f * twoal;

  const int idx_c2 = t * 100 + ((k < 10) ? k : 9) * 10;   // C2[t][kc][*] base
  __syncthreads();

  const int kk = (k == 0) ? 0 : (k - 1);
  // prefetch pointer-chase chain for first pair
  int p = blockIdx.x;
  int nb_pf = nbc_g[2 * p + node_s];
  int nbr_pf = neigh_g[(2 * p + node_s) * KN + kk];

#pragma unroll 1
  for (; p < NPAIRS; p += gridDim.x) {
    const int v = 2 * p + node_s;
    const int nb = nb_pf;
    const int srcn = (k == 0) ? v : (kk < nb ? nbr_pf : 0);
    const float s2x = s2x_g[srcn];
    const uint4* xr = (const uint4*)(xh + (size_t)srcn * 64);

    // prefetch next pair's chain (clamped; unused on last iteration)
    {
      int vn = 2 * (p + gridDim.x) + node_s;
      vn = vn < N_NODES ? vn : 0;
      nb_pf = nbc_g[vn];
      nbr_pf = neigh_g[vn * KN + kk];
    }

    // ---- per-lane M dot products (two 32B chunks to cap VGPR pressure) ----
    float acc[10];
#pragma unroll
    for (int m = 0; m < 10; m++) acc[m] = 0.0f;
    {
      const half_t* tfb = &tf_l[t * TF_STRIDE];
#pragma unroll 1
      for (int ch = 0; ch < 2; ch++) {
        uint4 xq[4];
#pragma unroll
        for (int c = 0; c < 4; c++) xq[c] = xr[ch * 4 + c];
#pragma unroll
        for (int c = 0; c < 4; c++) {
          half2_t x0 = __builtin_bit_cast(half2_t, xq[c].x);
          half2_t x1 = __builtin_bit_cast(half2_t, xq[c].y);
          half2_t x2 = __builtin_bit_cast(half2_t, xq[c].z);
          half2_t x3 = __builtin_bit_cast(half2_t, xq[c].w);
#pragma unroll
          for (int m = 0; m < 10; m++) {
            uint4 tq = *(const uint4*)&tfb[m * 64 + (ch * 4 + c) * 8];
            float a = acc[m];
            a = fdot2(__builtin_bit_cast(half2_t, tq.x), x0, a);
            a = fdot2(__builtin_bit_cast(half2_t, tq.y), x1, a);
            a = fdot2(__builtin_bit_cast(half2_t, tq.z), x2, a);
            a = fdot2(__builtin_bit_cast(half2_t, tq.w), x3, a);
            acc[m] = a;
          }
        }
      }
    }

    // ---- per-pair scalars ----
    const float inv = 1.0f / (float)(1 + nb);
    const float pk = (k <= nb) ? inv : 0.0f;
    const float hC1k = (k == 0) ? (float)nb * inv : ((k <= nb) ? inv : 0.0f);
    const float base = (beta * s2x + twoal * hC1k) * niep;
    const float ctm  = ctv10 * ((k == 0) ? (float)nb * inv : inv);

    float Ab[10];
#pragma unroll
    for (int j = 0; j < 5; j++) {
      float2 f1 = *(const float2*)&F1_l[t * 10 + 2 * j];
      Ab[2 * j]     = fmaf(cab, acc[2 * j],     f1.x + base);
      Ab[2 * j + 1] = fmaf(cab, acc[2 * j + 1], f1.y + base);
    }

    float K[10], vv[10];
    float u = 1.0f;
#pragma unroll
    for (int m = 0; m < 10; m++) vv[m] = 1.0f;

    // ---- outer 0: Tp = p (x) q -> tv from rowsum(C2) ----
#pragma unroll
    for (int j = 0; j < 5; j++) {
      float2 rs = *(const float2*)&rsc2_l[t * 10 + 2 * j];
      K[2 * j]     = __builtin_amdgcn_exp2f(fmaf(ctm, rs.x, Ab[2 * j]));
      K[2 * j + 1] = __builtin_amdgcn_exp2f(fmaf(ctm, rs.y, Ab[2 * j + 1]));
    }

#pragma unroll 1
    for (int o = 0; o < 3; o++) {
      // 5 drift-folded Sinkhorn iterations (kv split for shorter dep chain)
#pragma unroll 1
      for (int it = 0; it < 5; it++) {
        float kv0 = 0.0f, kv1 = 0.0f;
#pragma unroll
        for (int m = 0; m < 10; m += 2) {
          kv0 = fmaf(K[m],     vv[m],     kv0);
          kv1 = fmaf(K[m + 1], vv[m + 1], kv1);
        }
        u = pk * __builtin_amdgcn_rcpf(kv0 + kv1);
#pragma unroll
        for (int m = 0; m < 10; m++) {
          float w = sum16(K[m] * u);
          vv[m] = __builtin_amdgcn_rcpf(w);
        }
      }
      if (o == 2) break;
      // ---- site: recompute K from current Tp (tk' = 10*Tp) ----
      {
        float B = 0.0f, SB = 0.0f;
#pragma unroll
        for (int j = 0; j < 5; j++) {
          float2 c2p = *(const float2*)&c2_l[idx_c2 + 2 * j];
          float tka = K[2 * j] * vv[2 * j] * u;
          float tkb = K[2 * j + 1] * vv[2 * j + 1] * u;
          B  = fmaf(bcast16(tka), c2p.x, B);
          SB = fmaf(sum16(tka),   c2p.x, SB);
          B  = fmaf(bcast16(tkb), c2p.y, B);
          SB = fmaf(sum16(tkb),   c2p.y, SB);
        }
        if (k < 10) { bsb_l[grp][k][0] = B; bsb_l[grp][k][1] = SB; }
        __threadfence_block();
#pragma unroll
        for (int j = 0; j < 5; j++) {
          float4 bv = *(const float4*)&bsb_l[grp][2 * j][0];
          float tva = k0 ? (bv.y - bv.x) : bv.x;
          float tvb = k0 ? (bv.w - bv.z) : bv.z;
          K[2 * j]     = __builtin_amdgcn_exp2f(fmaf(ctv10, tva, Ab[2 * j]));
          K[2 * j + 1] = __builtin_amdgcn_exp2f(fmaf(ctv10, tvb, Ab[2 * j + 1]));
        }
        __threadfence_block();
      }
    }

    // ---- final: distance. coeff = c_a2d*Ab - alpha*cc - twoal*0.1*tv' ----
    {
      float tk[10];
      float B = 0.0f, SB = 0.0f;
#pragma unroll
      for (int j = 0; j < 5; j++) {
        float2 c2p = *(const float2*)&c2_l[idx_c2 + 2 * j];
        tk[2 * j]     = K[2 * j] * vv[2 * j] * u;
        tk[2 * j + 1] = K[2 * j + 1] * vv[2 * j + 1] * u;
        B  = fmaf(bcast16(tk[2 * j]), c2p.x, B);
        SB = fmaf(sum16(tk[2 * j]),   c2p.x, SB);
        B  = fmaf(bcast16(tk[2 * j + 1]), c2p.y, B);
        SB = fmaf(sum16(tk[2 * j + 1]),   c2p.y, SB);
      }
      if (k < 10) { bsb_l[grp][k][0] = B; bsb_l[grp][k][1] = SB; }
      __threadfence_block();
      float dd = 0.0f;
#pragma unroll
      for (int j = 0; j < 5; j++) {
        float4 bv = *(const float4*)&bsb_l[grp][2 * j][0];
        float2 h2 = *(const float2*)&hc2_l[t * 10 + 2 * j];
        float tva = k0 ? (bv.y - bv.x) : bv.x;
        float tvb = k0 ? (bv.w - bv.z) : bv.z;
        float c1a = fmaf(alpha, hC1k + h2.x, twoal01 * tva);
        float c1b = fmaf(alpha, hC1k + h2.y, twoal01 * tvb);
        float coa = fmaf(c_a2d, Ab[2 * j], -c1a);
        float cob = fmaf(c_a2d, Ab[2 * j + 1], -c1b);
        dd = fmaf(coa, tk[2 * j], dd);
        dd = fmaf(cob, tk[2 * j + 1], dd);
      }
      __threadfence_block();
      dd = sum16(dd * 0.1f);
      if (k == 0) out[v * 10 + t] = dd;
    }
  }
}

extern "C" void kernel_launch(void* const* d_in, const int* in_sizes, int n_in,
                              void* d_out, int out_size, void* d_ws, size_t ws_size,
                              hipStream_t stream) {
  const float* x  = (const float*)d_in[0];
  const int*   ei = (const int*)d_in[1];
  const float* c2 = (const float*)d_in[2];
  const float* tf = (const float*)d_in[3];
  const float* a0 = (const float*)d_in[4];
  float* out = (float*)d_out;
  char* ws = (char*)d_ws;
  int*    cnt    = (int*)(ws + OFF_CNT);
  int*    counts = (int*)(ws + OFF_COUNTS);
  double* stats  = (double*)(ws + OFF_STATS);
  int*    flag   = (int*)(ws + OFF_FLAG);
  int*    nbc    = (int*)(ws + OFF_NBC);
  int*    neigh  = (int*)(ws + OFF_NEIGH);
  int*    buf    = (int*)(ws + OFF_BUF);
  half_t* xh     = (half_t*)(ws + OFF_XH);
  float*  s2xh   = (float*)(ws + OFF_S2X);
  float*  params = (float*)(ws + OFF_PARAMS);
  (void)in_sizes; (void)n_in; (void)out_size; (void)ws_size;

  hipMemsetAsync(ws, 0, 160528, stream);   // zero cnt, counts, stats, flag
  k_scatter<<<N_EDGES / 256, 256, 0, stream>>>(ei, cnt, buf);
  k_select<<<(N_NODES * 64 + 255) / 256, 256, 0, stream>>>(ei, cnt, buf, nbc, neigh, counts);
  k_stats<<<STATS_BLOCKS, 256, 0, stream>>>(x, counts, stats, flag, xh, s2xh,
                                            tf, c2, a0, params);
  k_main<<<2500, 320, 0, stream>>>(xh, tf, c2, nbc, neigh, params, s2xh, out);
}

// Round 13
// 437.150 us; speedup vs baseline: 1.0725x; 1.0725x over previous
//
#include <hip/hip_runtime.h>

#define N_NODES 20000
#define NPAIRS  10000
#define N_EDGES 320000
#define CAP     64
#define KN      15

typedef _Float16 half_t;
typedef _Float16 half2_t __attribute__((ext_vector_type(2)));

// params float-index layout
#define P_ALPHA 0
#define P_BETA  1
#define P_IEPS2 2
#define P_EPS   3
#define P_HC2   16
#define P_RSC2  216
#define P_F1    316

// workspace byte offsets
#define OFF_CNT    0u             // 80 KB
#define OFF_S2X    80000u         // 80 KB (replaces old counts array)
#define OFF_STATS  160000u        // 65 doubles (520 B)
#define OFF_FLAG   160520u        // last-block-done counter
#define OFF_NBC    160528u
#define OFF_NEIGH  240528u
#define OFF_BUF    1440528u       // 5.12 MB
#define OFF_PARAMS 6560528u
#define MEMSET_LEN 160528u        // cnt + (s2x, harmless) + stats + flag

// tf_l per-template stride (halfs): dword stride 324 = 4 (mod 32)
#define TF_STRIDE 648

// ---- 16-lane reduction via DPP row_ror adds: pure VALU ----
template<int CTRL>
__device__ __forceinline__ float dpp_add(float v) {
  int s = __builtin_bit_cast(int, v);
  int r = __builtin_amdgcn_update_dpp(0, s, CTRL, 0xF, 0xF, true);
  return v + __builtin_bit_cast(float, r);
}
__device__ __forceinline__ float sum16(float v) {
  v = dpp_add<0x128>(v);   // row_ror:8
  v = dpp_add<0x124>(v);   // row_ror:4
  v = dpp_add<0x122>(v);   // row_ror:2
  v = dpp_add<0x121>(v);   // row_ror:1
  return v;
}
// ds_swizzle imm BitMode 0x010: new_lane = lane&0x10 -> broadcast k=0 of group
__device__ __forceinline__ float bcast16(float v) {
  return __builtin_bit_cast(float,
      __builtin_amdgcn_ds_swizzle(__builtin_bit_cast(int, v), 0x010));
}
__device__ __forceinline__ float fdot2(half2_t a, half2_t b, float c) {
  return __builtin_amdgcn_fdot2(a, b, c, false);
}
// force a wave-uniform float into an SGPR
__device__ __forceinline__ float sgpr(float v) {
  return __builtin_bit_cast(float,
      __builtin_amdgcn_readfirstlane(__builtin_bit_cast(int, v)));
}

// ---------------- kernel 1: scatter edge ids per source node ----------------
__global__ void k_scatter(const int* __restrict__ ei, int* __restrict__ cnt,
                          int* __restrict__ buf) {
  int e = blockIdx.x * blockDim.x + threadIdx.x;
  if (e >= N_EDGES) return;
  int s = ei[e];
  int slot = atomicAdd(&cnt[s], 1);
  if (slot < CAP) buf[s * CAP + slot] = e;
}

// ---- kernel 2: select 15 smallest edge ids + fused eps-stats + finalize ----
// wave-per-node (strided). Weighted x-sums computed directly from the
// selection (counts[u]*x[u] == sum_v [x[v] + sum_sel x[d] + (15-nb)x[0]]),
// so no counts array and no separate stats pass. s2xh (per-node ||f16 x||^2)
// computed from the self row. Last-finishing block runs the eps/F1 finalize.
#define SS_BLOCKS 320
__global__ void __launch_bounds__(256)
k_selstats(const int* __restrict__ ei, const int* __restrict__ cnt,
           const int* __restrict__ buf, const float* __restrict__ x,
           int* __restrict__ nbc_g, int* __restrict__ neigh,
           float* __restrict__ s2xh, double* __restrict__ stats,
           int* __restrict__ flag,
           const float* __restrict__ tf, const float* __restrict__ c2,
           const float* __restrict__ alpha0, float* __restrict__ params) {
  const int lane = threadIdx.x & 63;
  const int wid = threadIdx.x >> 6;
  const int* dst = ei + N_EDGES;
  const float x0 = x[lane];          // x[0,f] (lane = feature)
  const float x0sq = x0 * x0;
  float accx = 0.f, acc2 = 0.f;      // per-lane(feature) weighted sums

  for (int w = blockIdx.x * 4 + wid; w < N_NODES; w += SS_BLOCKS * 4) {
    int c = cnt[w];
    int cc = c < CAP ? c : CAP;
    int e = (lane < cc) ? buf[w * CAP + lane] : 0x7fffffff;
    int nb = c < KN ? c : KN;
    bool sel;
    if (cc <= KN) {
      sel = lane < cc;
    } else {
      int rank = 0;
      for (int j = 0; j < cc; j++) {      // cc is wave-uniform
        int ej = __shfl(e, j);
        rank += (ej < e) ? 1 : 0;
      }
      sel = (e != 0x7fffffff) && (rank < KN);  // distinct ids -> exactly 15
    }
    unsigned long long mask = __ballot(sel);
    int d = sel ? dst[e] : 0;
    if (sel) {
      int pos = __popcll(mask & ((1ull << lane) - 1ull));
      neigh[w * KN + pos] = d;
    }
    if (lane == 0) nbc_g[w] = nb;

    // ---- stats: lane = feature ----
    float sv = x[w * 64 + lane];
    {   // s2xh[w] = sum_f (f16(x))^2  (RTNE cast, matches k_main conversion)
      float hv = (float)(half_t)sv;
      float sq = hv * hv;
#pragma unroll
      for (int off = 32; off > 0; off >>= 1) sq += __shfl_xor(sq, off, 64);
      if (lane == 0) s2xh[w] = sq;
    }
    float ax = sv, a2 = sv * sv;
    unsigned long long m2 = mask;
#pragma unroll 1
    for (int r = 0; r < nb; r++) {       // nb == popcount(mask)
      int src_lane = __builtin_ctzll(m2);
      m2 &= m2 - 1;
      int dr = __shfl(d, src_lane);
      float nv = x[dr * 64 + lane];
      ax += nv;
      a2 = fmaf(nv, nv, a2);
    }
    float w0 = (float)(KN - nb);
    ax = fmaf(w0, x0, ax);
    a2 = fmaf(w0, x0sq, a2);
    accx += ax;
    acc2 += a2;
  }

  // ---- block reduction + global atomics ----
#pragma unroll
  for (int off = 32; off > 0; off >>= 1) acc2 += __shfl_xor(acc2, off, 64);
  __shared__ float redx[4][64];
  __shared__ float red2[4];
  __shared__ int lastsh;
  redx[wid][lane] = accx;
  if (lane == 0) red2[wid] = acc2;
  __syncthreads();
  int tid = threadIdx.x;
  if (tid < 64) {
    float s = redx[0][tid] + redx[1][tid] + redx[2][tid] + redx[3][tid];
    atomicAdd(&stats[1 + tid], (double)s);
  }
  if (tid == 0)
    atomicAdd(&stats[0], (double)(red2[0] + red2[1] + red2[2] + red2[3]));
  __syncthreads();
  if (tid == 0) {
    __threadfence();
    int old = atomicAdd(flag, 1);
    lastsh = (old == SS_BLOCKS - 1) ? 1 : 0;
  }
  __syncthreads();
  if (!lastsh) return;
  __threadfence();   // acquire: all blocks' stats atomics visible
  // ------- finalize (runs once, in the last-finishing block) -------
  __shared__ float sh[4];
  if (tid < 64) {
    float s = 0.f, s2 = 0.f;
    for (int tm = 0; tm < 100; tm++) { float v = tf[tm * 64 + tid]; s += v; s2 += v * v; }
    double inv16N = 1.0 / (double)(N_NODES * 16);
    double cross = (stats[1 + tid] * inv16N) * ((double)s / 100.0);
    double B = (double)s2 / 100.0;
    double term = B - 2.0 * cross;
#pragma unroll
    for (int off = 32; off > 0; off >>= 1) term += __shfl_xor(term, off, 64);
    if (tid == 0) {
      double A = stats[0] * inv16N;
      double meanM = A + term;
      float eps = (float)(0.05 * meanM) + 1e-6f;
      float a0 = alpha0[0];
      float alpha = 1.f / (1.f + expf(-a0));
      params[P_ALPHA] = alpha;
      params[P_BETA]  = 1.f - alpha;
      params[P_IEPS2] = 1.4426950408889634f / eps;
      params[P_EPS]   = eps;
      sh[0] = alpha; sh[1] = 1.f - alpha; sh[2] = 1.4426950408889634f / eps;
    }
  }
  __syncthreads();
  if (tid < 100) {
    float alpha = sh[0], beta = sh[1], ieps2 = sh[2];
    int t = tid / 10, mm = tid % 10;
    float h = 0.f;
    for (int r = 0; r < 10; r++) { float cv = c2[t * 100 + mm * 10 + r]; h += cv * cv; }
    float hc2v = 0.1f * h;
    params[P_HC2 + tid] = hc2v;
    float s2 = 0.f;
    for (int f = 0; f < 64; f++) { float v = tf[tid * 64 + f]; s2 += v * v; }
    float rs = 0.f;
    for (int m2_ = 0; m2_ < 10; m2_++) rs += c2[t * 100 + mm * 10 + m2_];
    params[P_RSC2 + tid] = rs;
    params[P_F1 + tid] = (beta * s2 + 2.0f * alpha * hc2v) * (-ieps2);
  }
}

// --------- kernel 3: single-pair fused M + drift-folded Sinkhorn ------------
// lane = (node_s, t, k). x loaded as f32 and converted to f16 in-kernel
// (RTNE, numerically identical to the old pre-converted xh path).
__global__ void __launch_bounds__(320, 6)
k_main(const float* __restrict__ x, const float* __restrict__ tf_g,
       const float* __restrict__ c2_g, const int* __restrict__ nbc_g,
       const int* __restrict__ neigh_g, const float* __restrict__ params,
       const float* __restrict__ s2x_g, float* __restrict__ out) {
  __shared__ __align__(16) half_t tf_l[10 * TF_STRIDE];   // 12.96 KB
  __shared__ __align__(16) float c2_l[1000];              // 4 KB
  __shared__ __align__(16) float hc2_l[100];
  __shared__ __align__(16) float rsc2_l[100];
  __shared__ __align__(16) float F1_l[100];
  __shared__ __align__(16) float bsb_l[20][10][2];

  const int tid = threadIdx.x;
  const int node_s = tid / 160;
  const int s = tid % 160;
  const int t = s >> 4;
  const int k = s & 15;
  const bool k0 = (k == 0);
  const int grp = node_s * 10 + t;

  for (int i = tid; i < 6400; i += 320) {
    int tt = i / 640, rem = i - tt * 640;
    tf_l[tt * TF_STRIDE + rem] = (half_t)tf_g[i];
  }
  for (int i = tid; i < 1000; i += 320) c2_l[i] = c2_g[i];
  if (tid < 100) {
    hc2_l[tid]  = params[P_HC2 + tid];
    rsc2_l[tid] = params[P_RSC2 + tid];
    F1_l[tid]   = params[P_F1 + tid];
  }

  // wave-uniform constants -> SGPRs
  const float alpha = sgpr(params[P_ALPHA]);
  const float beta  = sgpr(params[P_BETA]);
  const float ieps2 = sgpr(params[P_IEPS2]);
  const float eps   = sgpr(params[P_EPS]);
  const float niep  = -ieps2;
  const float twoal = 2.0f * alpha;
  const float ctv10 = 0.2f * twoal * ieps2;    // = ctv*0.1 (drift-compensated)
  const float cab   = 2.0f * beta * ieps2;
  const float c_a2d = -eps * 0.69314718056f;   // Ab -> (beta*M + 2a*cc)
  const float twoal01 = 0.1f * twoal;

  const int idx_c2 = t * 100 + ((k < 10) ? k : 9) * 10;   // C2[t][kc][*] base
  __syncthreads();

  const int kk = (k == 0) ? 0 : (k - 1);
  // prefetch pointer-chase chain for first pair
  int p = blockIdx.x;
  int nb_pf = nbc_g[2 * p + node_s];
  int nbr_pf = neigh_g[(2 * p + node_s) * KN + kk];

#pragma unroll 1
  for (; p < NPAIRS; p += gridDim.x) {
    const int v = 2 * p + node_s;
    const int nb = nb_pf;
    const int srcn = (k == 0) ? v : (kk < nb ? nbr_pf : 0);
    const float s2x = s2x_g[srcn];
    const float4* xr = (const float4*)(x + (size_t)srcn * 64);

    // prefetch next pair's chain (clamped; unused on last iteration)
    {
      int vn = 2 * (p + gridDim.x) + node_s;
      vn = vn < N_NODES ? vn : 0;
      nb_pf = nbc_g[vn];
      nbr_pf = neigh_g[vn * KN + kk];
    }

    // ---- per-lane M dot products: f32 load -> f16 convert -> fdot2 ----
    float acc[10];
#pragma unroll
    for (int m = 0; m < 10; m++) acc[m] = 0.0f;
    {
      const half_t* tfb = &tf_l[t * TF_STRIDE];
#pragma unroll 1
      for (int ch = 0; ch < 4; ch++) {           // 4 chunks of 16 floats
        float4 f0 = xr[ch * 4 + 0];
        float4 f1 = xr[ch * 4 + 1];
        float4 f2 = xr[ch * 4 + 2];
        float4 f3 = xr[ch * 4 + 3];
        half2_t x0 = { (half_t)f0.x, (half_t)f0.y };
        half2_t x1 = { (half_t)f0.z, (half_t)f0.w };
        half2_t x2 = { (half_t)f1.x, (half_t)f1.y };
        half2_t x3 = { (half_t)f1.z, (half_t)f1.w };
        half2_t x4 = { (half_t)f2.x, (half_t)f2.y };
        half2_t x5 = { (half_t)f2.z, (half_t)f2.w };
        half2_t x6 = { (half_t)f3.x, (half_t)f3.y };
        half2_t x7 = { (half_t)f3.z, (half_t)f3.w };
#pragma unroll
        for (int m = 0; m < 10; m++) {
          uint4 tqa = *(const uint4*)&tfb[m * 64 + ch * 16];
          uint4 tqb = *(const uint4*)&tfb[m * 64 + ch * 16 + 8];
          float a = acc[m];
          a = fdot2(__builtin_bit_cast(half2_t, tqa.x), x0, a);
          a = fdot2(__builtin_bit_cast(half2_t, tqa.y), x1, a);
          a = fdot2(__builtin_bit_cast(half2_t, tqa.z), x2, a);
          a = fdot2(__builtin_bit_cast(half2_t, tqa.w), x3, a);
          a = fdot2(__builtin_bit_cast(half2_t, tqb.x), x4, a);
          a = fdot2(__builtin_bit_cast(half2_t, tqb.y), x5, a);
          a = fdot2(__builtin_bit_cast(half2_t, tqb.z), x6, a);
          a = fdot2(__builtin_bit_cast(half2_t, tqb.w), x7, a);
          acc[m] = a;
        }
      }
    }

    // ---- per-pair scalars ----
    const float inv = 1.0f / (float)(1 + nb);
    const float pk = (k <= nb) ? inv : 0.0f;
    const float hC1k = (k == 0) ? (float)nb * inv : ((k <= nb) ? inv : 0.0f);
    const float base = (beta * s2x + twoal * hC1k) * niep;
    const float ctm  = ctv10 * ((k == 0) ? (float)nb * inv : inv);

    float Ab[10];
#pragma unroll
    for (int j = 0; j < 5; j++) {
      float2 f1v = *(const float2*)&F1_l[t * 10 + 2 * j];
      Ab[2 * j]     = fmaf(cab, acc[2 * j],     f1v.x + base);
      Ab[2 * j + 1] = fmaf(cab, acc[2 * j + 1], f1v.y + base);
    }

    float K[10], vv[10];
    float u = 1.0f;
#pragma unroll
    for (int m = 0; m < 10; m++) vv[m] = 1.0f;

    // ---- outer 0: Tp = p (x) q -> tv from rowsum(C2) ----
#pragma unroll
    for (int j = 0; j < 5; j++) {
      float2 rs = *(const float2*)&rsc2_l[t * 10 + 2 * j];
      K[2 * j]     = __builtin_amdgcn_exp2f(fmaf(ctm, rs.x, Ab[2 * j]));
      K[2 * j + 1] = __builtin_amdgcn_exp2f(fmaf(ctm, rs.y, Ab[2 * j + 1]));
    }

#pragma unroll 1
    for (int o = 0; o < 3; o++) {
      // 5 drift-folded Sinkhorn iterations (kv split for shorter dep chain)
#pragma unroll 1
      for (int it = 0; it < 5; it++) {
        float kv0 = 0.0f, kv1 = 0.0f;
#pragma unroll
        for (int m = 0; m < 10; m += 2) {
          kv0 = fmaf(K[m],     vv[m],     kv0);
          kv1 = fmaf(K[m + 1], vv[m + 1], kv1);
        }
        u = pk * __builtin_amdgcn_rcpf(kv0 + kv1);
#pragma unroll
        for (int m = 0; m < 10; m++) {
          float w = sum16(K[m] * u);
          vv[m] = __builtin_amdgcn_rcpf(w);
        }
      }
      if (o == 2) break;
      // ---- site: recompute K from current Tp (tk' = 10*Tp) ----
      {
        float B = 0.0f, SB = 0.0f;
#pragma unroll
        for (int j = 0; j < 5; j++) {
          float2 c2p = *(const float2*)&c2_l[idx_c2 + 2 * j];
          float tka = K[2 * j] * vv[2 * j] * u;
          float tkb = K[2 * j + 1] * vv[2 * j + 1] * u;
          B  = fmaf(bcast16(tka), c2p.x, B);
          SB = fmaf(sum16(tka),   c2p.x, SB);
          B  = fmaf(bcast16(tkb), c2p.y, B);
          SB = fmaf(sum16(tkb),   c2p.y, SB);
        }
        if (k < 10) { bsb_l[grp][k][0] = B; bsb_l[grp][k][1] = SB; }
        __threadfence_block();
#pragma unroll
        for (int j = 0; j < 5; j++) {
          float4 bv = *(const float4*)&bsb_l[grp][2 * j][0];
          float tva = k0 ? (bv.y - bv.x) : bv.x;
          float tvb = k0 ? (bv.w - bv.z) : bv.z;
          K[2 * j]     = __builtin_amdgcn_exp2f(fmaf(ctv10, tva, Ab[2 * j]));
          K[2 * j + 1] = __builtin_amdgcn_exp2f(fmaf(ctv10, tvb, Ab[2 * j + 1]));
        }
        __threadfence_block();
      }
    }

    // ---- final: distance. coeff = c_a2d*Ab - alpha*cc - twoal*0.1*tv' ----
    {
      float tk[10];
      float B = 0.0f, SB = 0.0f;
#pragma unroll
      for (int j = 0; j < 5; j++) {
        float2 c2p = *(const float2*)&c2_l[idx_c2 + 2 * j];
        tk[2 * j]     = K[2 * j] * vv[2 * j] * u;
        tk[2 * j + 1] = K[2 * j + 1] * vv[2 * j + 1] * u;
        B  = fmaf(bcast16(tk[2 * j]), c2p.x, B);
        SB = fmaf(sum16(tk[2 * j]),   c2p.x, SB);
        B  = fmaf(bcast16(tk[2 * j + 1]), c2p.y, B);
        SB = fmaf(sum16(tk[2 * j + 1]),   c2p.y, SB);
      }
      if (k < 10) { bsb_l[grp][k][0] = B; bsb_l[grp][k][1] = SB; }
      __threadfence_block();
      float dd = 0.0f;
#pragma unroll
      for (int j = 0; j < 5; j++) {
        float4 bv = *(const float4*)&bsb_l[grp][2 * j][0];
        float2 h2 = *(const float2*)&hc2_l[t * 10 + 2 * j];
        float tva = k0 ? (bv.y - bv.x) : bv.x;
        float tvb = k0 ? (bv.w - bv.z) : bv.z;
        float c1a = fmaf(alpha, hC1k + h2.x, twoal01 * tva);
        float c1b = fmaf(alpha, hC1k + h2.y, twoal01 * tvb);
        float coa = fmaf(c_a2d, Ab[2 * j], -c1a);
        float cob = fmaf(c_a2d, Ab[2 * j + 1], -c1b);
        dd = fmaf(coa, tk[2 * j], dd);
        dd = fmaf(cob, tk[2 * j + 1], dd);
      }
      __threadfence_block();
      dd = sum16(dd * 0.1f);
      if (k == 0) out[v * 10 + t] = dd;
    }
  }
}

extern "C" void kernel_launch(void* const* d_in, const int* in_sizes, int n_in,
                              void* d_out, int out_size, void* d_ws, size_t ws_size,
                              hipStream_t stream) {
  const float* x  = (const float*)d_in[0];
  const int*   ei = (const int*)d_in[1];
  const float* c2 = (const float*)d_in[2];
  const float* tf = (const float*)d_in[3];
  const float* a0 = (const float*)d_in[4];
  float* out = (float*)d_out;
  char* ws = (char*)d_ws;
  int*    cnt    = (int*)(ws + OFF_CNT);
  float*  s2xh   = (float*)(ws + OFF_S2X);
  double* stats  = (double*)(ws + OFF_STATS);
  int*    flag   = (int*)(ws + OFF_FLAG);
  int*    nbc    = (int*)(ws + OFF_NBC);
  int*    neigh  = (int*)(ws + OFF_NEIGH);
  int*    buf    = (int*)(ws + OFF_BUF);
  float*  params = (float*)(ws + OFF_PARAMS);
  (void)in_sizes; (void)n_in; (void)out_size; (void)ws_size;

  hipMemsetAsync(ws, 0, MEMSET_LEN, stream);   // zero cnt, stats, flag
  k_scatter<<<N_EDGES / 256, 256, 0, stream>>>(ei, cnt, buf);
  k_selstats<<<SS_BLOCKS, 256, 0, stream>>>(ei, cnt, buf, x, nbc, neigh,
                                            s2xh, stats, flag, tf, c2, a0, params);
  k_main<<<2500, 320, 0, stream>>>(x, tf, c2, nbc, neigh, params, s2xh, out);
}

// Round 14
// 401.001 us; speedup vs baseline: 1.1691x; 1.0901x over previous
//
#include <hip/hip_runtime.h>

#define N_NODES 20000
#define NPAIRS  10000
#define N_EDGES 320000
#define CAP     64
#define KN      15

typedef _Float16 half_t;
typedef _Float16 half2_t __attribute__((ext_vector_type(2)));

// params float-index layout
#define P_ALPHA 0
#define P_BETA  1
#define P_IEPS2 2
#define P_EPS   3
#define P_HC2   16
#define P_RSC2  216
#define P_F1    316

// workspace byte offsets
#define OFF_CNT    0u             // 80 KB
#define OFF_S2X    80000u         // 80 KB
#define OFF_STATS  160000u        // 65 doubles (520 B)
#define OFF_FLAG   160520u        // last-block-done counter
#define OFF_NBC    160528u
#define OFF_NEIGH  240528u
#define OFF_BUF    1440528u       // 5.12 MB
#define OFF_PARAMS 6560528u
#define MEMSET_LEN 160528u        // cnt + s2x(harmless) + stats + flag

// tf_l per-template stride (halfs): dword stride 324 = 4 (mod 32)
#define TF_STRIDE 648

// ---- 16-lane reduction via DPP row_ror adds: pure VALU ----
template<int CTRL>
__device__ __forceinline__ float dpp_add(float v) {
  int s = __builtin_bit_cast(int, v);
  int r = __builtin_amdgcn_update_dpp(0, s, CTRL, 0xF, 0xF, true);
  return v + __builtin_bit_cast(float, r);
}
__device__ __forceinline__ float sum16(float v) {
  v = dpp_add<0x128>(v);   // row_ror:8
  v = dpp_add<0x124>(v);   // row_ror:4
  v = dpp_add<0x122>(v);   // row_ror:2
  v = dpp_add<0x121>(v);   // row_ror:1
  return v;
}
// ds_swizzle imm BitMode 0x010: new_lane = lane&0x10 -> broadcast k=0 of group
__device__ __forceinline__ float bcast16(float v) {
  return __builtin_bit_cast(float,
      __builtin_amdgcn_ds_swizzle(__builtin_bit_cast(int, v), 0x010));
}
__device__ __forceinline__ float fdot2(half2_t a, half2_t b, float c) {
  return __builtin_amdgcn_fdot2(a, b, c, false);
}
// force a wave-uniform float into an SGPR
__device__ __forceinline__ float sgpr(float v) {
  return __builtin_bit_cast(float,
      __builtin_amdgcn_readfirstlane(__builtin_bit_cast(int, v)));
}

// ---------------- kernel 1: scatter edge ids per source node ----------------
__global__ void k_scatter(const int* __restrict__ ei, int* __restrict__ cnt,
                          int* __restrict__ buf) {
  int e = blockIdx.x * blockDim.x + threadIdx.x;
  if (e >= N_EDGES) return;
  int s = ei[e];
  int slot = atomicAdd(&cnt[s], 1);
  if (slot < CAP) buf[s * CAP + slot] = e;
}

// ---- kernel 2: select 15 smallest edge ids + fused eps-stats + finalize ----
// wave-per-node, 4 nodes/wave (SS_BLOCKS=1250). Neighbor indices staged
// through LDS so the 15 stats row-loads issue independently (MLP) instead of
// a serial ctz/shfl/load pointer chase.
#define SS_BLOCKS 1250
__global__ void __launch_bounds__(256)
k_selstats(const int* __restrict__ ei, const int* __restrict__ cnt,
           const int* __restrict__ buf, const float* __restrict__ x,
           int* __restrict__ nbc_g, int* __restrict__ neigh,
           float* __restrict__ s2xh, double* __restrict__ stats,
           int* __restrict__ flag,
           const float* __restrict__ tf, const float* __restrict__ c2,
           const float* __restrict__ alpha0, float* __restrict__ params) {
  const int lane = threadIdx.x & 63;
  const int wid = threadIdx.x >> 6;
  const int* dst = ei + N_EDGES;
  const float x0 = x[lane];          // x[0,f] (lane = feature)
  const float x0sq = x0 * x0;
  float accx = 0.f, acc2 = 0.f;      // per-lane(feature) weighted sums
  __shared__ int dsh[4][16];         // per-wave staging of selected neighbors

  for (int w = blockIdx.x * 4 + wid; w < N_NODES; w += SS_BLOCKS * 4) {
    int c = cnt[w];
    int cc = c < CAP ? c : CAP;
    int e = (lane < cc) ? buf[w * CAP + lane] : 0x7fffffff;
    int nb = c < KN ? c : KN;
    bool sel;
    if (cc <= KN) {
      sel = lane < cc;
    } else {
      int rank = 0;
      for (int j = 0; j < cc; j++) {      // cc is wave-uniform
        int ej = __shfl(e, j);
        rank += (ej < e) ? 1 : 0;
      }
      sel = (e != 0x7fffffff) && (rank < KN);  // distinct ids -> exactly 15
    }
    unsigned long long mask = __ballot(sel);
    int d = sel ? dst[e] : 0;
    if (sel) {
      int pos = __popcll(mask & ((1ull << lane) - 1ull));
      neigh[w * KN + pos] = d;
      dsh[wid][pos] = d;               // intra-wave LDS staging
    }
    if (lane == 0) nbc_g[w] = nb;

    // ---- stats: lane = feature ----
    float sv = x[w * 64 + lane];
    {   // s2xh[w] = sum_f (f16(x))^2  (RTNE cast, matches k_main conversion)
      float hv = (float)(half_t)sv;
      float sq = hv * hv;
#pragma unroll
      for (int off = 32; off > 0; off >>= 1) sq += __shfl_xor(sq, off, 64);
      if (lane == 0) s2xh[w] = sq;
    }
    float ax = sv, a2 = sv * sv;
    // read all (up to 15) neighbor indices, then issue loads independently
    int idx[KN];
#pragma unroll
    for (int r = 0; r < KN; r++) idx[r] = dsh[wid][r];   // garbage beyond nb: unused
#pragma unroll
    for (int r = 0; r < KN; r++) {
      if (r < nb) {                        // nb is wave-uniform -> uniform branch
        float nv = x[(size_t)idx[r] * 64 + lane];
        ax += nv;
        a2 = fmaf(nv, nv, a2);
      }
    }
    float w0 = (float)(KN - nb);
    ax = fmaf(w0, x0, ax);
    a2 = fmaf(w0, x0sq, a2);
    accx += ax;
    acc2 += a2;
  }

  // ---- block reduction + global atomics ----
#pragma unroll
  for (int off = 32; off > 0; off >>= 1) acc2 += __shfl_xor(acc2, off, 64);
  __shared__ float redx[4][64];
  __shared__ float red2[4];
  __shared__ int lastsh;
  redx[wid][lane] = accx;
  if (lane == 0) red2[wid] = acc2;
  __syncthreads();
  int tid = threadIdx.x;
  if (tid < 64) {
    float s = redx[0][tid] + redx[1][tid] + redx[2][tid] + redx[3][tid];
    atomicAdd(&stats[1 + tid], (double)s);
  }
  if (tid == 0)
    atomicAdd(&stats[0], (double)(red2[0] + red2[1] + red2[2] + red2[3]));
  __syncthreads();
  if (tid == 0) {
    __threadfence();
    int old = atomicAdd(flag, 1);
    lastsh = (old == SS_BLOCKS - 1) ? 1 : 0;
  }
  __syncthreads();
  if (!lastsh) return;
  __threadfence();   // acquire: all blocks' stats atomics visible
  // ------- finalize (runs once, in the last-finishing block) -------
  __shared__ float sh[4];
  if (tid < 64) {
    float s = 0.f, s2 = 0.f;
    for (int tm = 0; tm < 100; tm++) { float v = tf[tm * 64 + tid]; s += v; s2 += v * v; }
    double inv16N = 1.0 / (double)(N_NODES * 16);
    double cross = (stats[1 + tid] * inv16N) * ((double)s / 100.0);
    double B = (double)s2 / 100.0;
    double term = B - 2.0 * cross;
#pragma unroll
    for (int off = 32; off > 0; off >>= 1) term += __shfl_xor(term, off, 64);
    if (tid == 0) {
      double A = stats[0] * inv16N;
      double meanM = A + term;
      float eps = (float)(0.05 * meanM) + 1e-6f;
      float a0 = alpha0[0];
      float alpha = 1.f / (1.f + expf(-a0));
      params[P_ALPHA] = alpha;
      params[P_BETA]  = 1.f - alpha;
      params[P_IEPS2] = 1.4426950408889634f / eps;
      params[P_EPS]   = eps;
      sh[0] = alpha; sh[1] = 1.f - alpha; sh[2] = 1.4426950408889634f / eps;
    }
  }
  __syncthreads();
  if (tid < 100) {
    float alpha = sh[0], beta = sh[1], ieps2 = sh[2];
    int t = tid / 10, mm = tid % 10;
    float h = 0.f;
    for (int r = 0; r < 10; r++) { float cv = c2[t * 100 + mm * 10 + r]; h += cv * cv; }
    float hc2v = 0.1f * h;
    params[P_HC2 + tid] = hc2v;
    float s2 = 0.f;
    for (int f = 0; f < 64; f++) { float v = tf[tid * 64 + f]; s2 += v * v; }
    float rs = 0.f;
    for (int m2_ = 0; m2_ < 10; m2_++) rs += c2[t * 100 + mm * 10 + m2_];
    params[P_RSC2 + tid] = rs;
    params[P_F1 + tid] = (beta * s2 + 2.0f * alpha * hc2v) * (-ieps2);
  }
}

// --------- kernel 3: single-pair fused M + drift-folded Sinkhorn ------------
// lane = (node_s, t, k). x loaded as f32, converted to f16 in-kernel (RTNE).
__global__ void __launch_bounds__(320, 6)
k_main(const float* __restrict__ x, const float* __restrict__ tf_g,
       const float* __restrict__ c2_g, const int* __restrict__ nbc_g,
       const int* __restrict__ neigh_g, const float* __restrict__ params,
       const float* __restrict__ s2x_g, float* __restrict__ out) {
  __shared__ __align__(16) half_t tf_l[10 * TF_STRIDE];   // 12.96 KB
  __shared__ __align__(16) float c2_l[1000];              // 4 KB
  __shared__ __align__(16) float hc2_l[100];
  __shared__ __align__(16) float rsc2_l[100];
  __shared__ __align__(16) float F1_l[100];
  __shared__ __align__(16) float bsb_l[20][10][2];

  const int tid = threadIdx.x;
  const int node_s = tid / 160;
  const int s = tid % 160;
  const int t = s >> 4;
  const int k = s & 15;
  const bool k0 = (k == 0);
  const int grp = node_s * 10 + t;

  for (int i = tid; i < 6400; i += 320) {
    int tt = i / 640, rem = i - tt * 640;
    tf_l[tt * TF_STRIDE + rem] = (half_t)tf_g[i];
  }
  for (int i = tid; i < 1000; i += 320) c2_l[i] = c2_g[i];
  if (tid < 100) {
    hc2_l[tid]  = params[P_HC2 + tid];
    rsc2_l[tid] = params[P_RSC2 + tid];
    F1_l[tid]   = params[P_F1 + tid];
  }

  // wave-uniform constants -> SGPRs
  const float alpha = sgpr(params[P_ALPHA]);
  const float beta  = sgpr(params[P_BETA]);
  const float ieps2 = sgpr(params[P_IEPS2]);
  const float eps   = sgpr(params[P_EPS]);
  const float niep  = -ieps2;
  const float twoal = 2.0f * alpha;
  const float ctv10 = 0.2f * twoal * ieps2;    // = ctv*0.1 (drift-compensated)
  const float cab   = 2.0f * beta * ieps2;
  const float c_a2d = -eps * 0.69314718056f;   // Ab -> (beta*M + 2a*cc)
  const float twoal01 = 0.1f * twoal;

  const int idx_c2 = t * 100 + ((k < 10) ? k : 9) * 10;   // C2[t][kc][*] base
  __syncthreads();

  const int kk = (k == 0) ? 0 : (k - 1);
  // prefetch pointer-chase chain for first pair
  int p = blockIdx.x;
  int nb_pf = nbc_g[2 * p + node_s];
  int nbr_pf = neigh_g[(2 * p + node_s) * KN + kk];

#pragma unroll 1
  for (; p < NPAIRS; p += gridDim.x) {
    const int v = 2 * p + node_s;
    const int nb = nb_pf;
    const int srcn = (k == 0) ? v : (kk < nb ? nbr_pf : 0);
    const float s2x = s2x_g[srcn];
    const float4* xr = (const float4*)(x + (size_t)srcn * 64);

    // prefetch next pair's chain (clamped; unused on last iteration)
    {
      int vn = 2 * (p + gridDim.x) + node_s;
      vn = vn < N_NODES ? vn : 0;
      nb_pf = nbc_g[vn];
      nbr_pf = neigh_g[vn * KN + kk];
    }

    // ---- per-lane M dot products: f32 load -> f16 convert -> fdot2 ----
    float acc[10];
#pragma unroll
    for (int m = 0; m < 10; m++) acc[m] = 0.0f;
    {
      const half_t* tfb = &tf_l[t * TF_STRIDE];
#pragma unroll 1
      for (int ch = 0; ch < 4; ch++) {           // 4 chunks of 16 floats
        float4 f0 = xr[ch * 4 + 0];
        float4 f1 = xr[ch * 4 + 1];
        float4 f2 = xr[ch * 4 + 2];
        float4 f3 = xr[ch * 4 + 3];
        half2_t x0 = { (half_t)f0.x, (half_t)f0.y };
        half2_t x1 = { (half_t)f0.z, (half_t)f0.w };
        half2_t x2 = { (half_t)f1.x, (half_t)f1.y };
        half2_t x3 = { (half_t)f1.z, (half_t)f1.w };
        half2_t x4 = { (half_t)f2.x, (half_t)f2.y };
        half2_t x5 = { (half_t)f2.z, (half_t)f2.w };
        half2_t x6 = { (half_t)f3.x, (half_t)f3.y };
        half2_t x7 = { (half_t)f3.z, (half_t)f3.w };
#pragma unroll
        for (int m = 0; m < 10; m++) {
          uint4 tqa = *(const uint4*)&tfb[m * 64 + ch * 16];
          uint4 tqb = *(const uint4*)&tfb[m * 64 + ch * 16 + 8];
          float a = acc[m];
          a = fdot2(__builtin_bit_cast(half2_t, tqa.x), x0, a);
          a = fdot2(__builtin_bit_cast(half2_t, tqa.y), x1, a);
          a = fdot2(__builtin_bit_cast(half2_t, tqa.z), x2, a);
          a = fdot2(__builtin_bit_cast(half2_t, tqa.w), x3, a);
          a = fdot2(__builtin_bit_cast(half2_t, tqb.x), x4, a);
          a = fdot2(__builtin_bit_cast(half2_t, tqb.y), x5, a);
          a = fdot2(__builtin_bit_cast(half2_t, tqb.z), x6, a);
          a = fdot2(__builtin_bit_cast(half2_t, tqb.w), x7, a);
          acc[m] = a;
        }
      }
    }

    // ---- per-pair scalars ----
    const float inv = 1.0f / (float)(1 + nb);
    const float pk = (k <= nb) ? inv : 0.0f;
    const float hC1k = (k == 0) ? (float)nb * inv : ((k <= nb) ? inv : 0.0f);
    const float base = (beta * s2x + twoal * hC1k) * niep;
    const float ctm  = ctv10 * ((k == 0) ? (float)nb * inv : inv);

    float Ab[10];
#pragma unroll
    for (int j = 0; j < 5; j++) {
      float2 f1v = *(const float2*)&F1_l[t * 10 + 2 * j];
      Ab[2 * j]     = fmaf(cab, acc[2 * j],     f1v.x + base);
      Ab[2 * j + 1] = fmaf(cab, acc[2 * j + 1], f1v.y + base);
    }

    float K[10], vv[10];
    float u = 1.0f;
#pragma unroll
    for (int m = 0; m < 10; m++) vv[m] = 1.0f;

    // ---- outer 0: Tp = p (x) q -> tv from rowsum(C2) ----
#pragma unroll
    for (int j = 0; j < 5; j++) {
      float2 rs = *(const float2*)&rsc2_l[t * 10 + 2 * j];
      K[2 * j]     = __builtin_amdgcn_exp2f(fmaf(ctm, rs.x, Ab[2 * j]));
      K[2 * j + 1] = __builtin_amdgcn_exp2f(fmaf(ctm, rs.y, Ab[2 * j + 1]));
    }

#pragma unroll 1
    for (int o = 0; o < 3; o++) {
      // 5 drift-folded Sinkhorn iterations (kv split for shorter dep chain)
#pragma unroll 1
      for (int it = 0; it < 5; it++) {
        float kv0 = 0.0f, kv1 = 0.0f;
#pragma unroll
        for (int m = 0; m < 10; m += 2) {
          kv0 = fmaf(K[m],     vv[m],     kv0);
          kv1 = fmaf(K[m + 1], vv[m + 1], kv1);
        }
        u = pk * __builtin_amdgcn_rcpf(kv0 + kv1);
#pragma unroll
        for (int m = 0; m < 10; m++) {
          float w = sum16(K[m] * u);
          vv[m] = __builtin_amdgcn_rcpf(w);
        }
      }
      if (o == 2) break;
      // ---- site: recompute K from current Tp (tk' = 10*Tp) ----
      {
        float B = 0.0f, SB = 0.0f;
#pragma unroll
        for (int j = 0; j < 5; j++) {
          float2 c2p = *(const float2*)&c2_l[idx_c2 + 2 * j];
          float tka = K[2 * j] * vv[2 * j] * u;
          float tkb = K[2 * j + 1] * vv[2 * j + 1] * u;
          B  = fmaf(bcast16(tka), c2p.x, B);
          SB = fmaf(sum16(tka),   c2p.x, SB);
          B  = fmaf(bcast16(tkb), c2p.y, B);
          SB = fmaf(sum16(tkb),   c2p.y, SB);
        }
        if (k < 10) { bsb_l[grp][k][0] = B; bsb_l[grp][k][1] = SB; }
        __threadfence_block();
#pragma unroll
        for (int j = 0; j < 5; j++) {
          float4 bv = *(const float4*)&bsb_l[grp][2 * j][0];
          float tva = k0 ? (bv.y - bv.x) : bv.x;
          float tvb = k0 ? (bv.w - bv.z) : bv.z;
          K[2 * j]     = __builtin_amdgcn_exp2f(fmaf(ctv10, tva, Ab[2 * j]));
          K[2 * j + 1] = __builtin_amdgcn_exp2f(fmaf(ctv10, tvb, Ab[2 * j + 1]));
        }
        __threadfence_block();
      }
    }

    // ---- final: distance. coeff = c_a2d*Ab - alpha*cc - twoal*0.1*tv' ----
    {
      float tk[10];
      float B = 0.0f, SB = 0.0f;
#pragma unroll
      for (int j = 0; j < 5; j++) {
        float2 c2p = *(const float2*)&c2_l[idx_c2 + 2 * j];
        tk[2 * j]     = K[2 * j] * vv[2 * j] * u;
        tk[2 * j + 1] = K[2 * j + 1] * vv[2 * j + 1] * u;
        B  = fmaf(bcast16(tk[2 * j]), c2p.x, B);
        SB = fmaf(sum16(tk[2 * j]),   c2p.x, SB);
        B  = fmaf(bcast16(tk[2 * j + 1]), c2p.y, B);
        SB = fmaf(sum16(tk[2 * j + 1]),   c2p.y, SB);
      }
      if (k < 10) { bsb_l[grp][k][0] = B; bsb_l[grp][k][1] = SB; }
      __threadfence_block();
      float dd = 0.0f;
#pragma unroll
      for (int j = 0; j < 5; j++) {
        float4 bv = *(const float4*)&bsb_l[grp][2 * j][0];
        float2 h2 = *(const float2*)&hc2_l[t * 10 + 2 * j];
        float tva = k0 ? (bv.y - bv.x) : bv.x;
        float tvb = k0 ? (bv.w - bv.z) : bv.z;
        float c1a = fmaf(alpha, hC1k + h2.x, twoal01 * tva);
        float c1b = fmaf(alpha, hC1k + h2.y, twoal01 * tvb);
        float coa = fmaf(c_a2d, Ab[2 * j], -c1a);
        float cob = fmaf(c_a2d, Ab[2 * j + 1], -c1b);
        dd = fmaf(coa, tk[2 * j], dd);
        dd = fmaf(cob, tk[2 * j + 1], dd);
      }
      __threadfence_block();
      dd = sum16(dd * 0.1f);
      if (k == 0) out[v * 10 + t] = dd;
    }
  }
}

extern "C" void kernel_launch(void* const* d_in, const int* in_sizes, int n_in,
                              void* d_out, int out_size, void* d_ws, size_t ws_size,
                              hipStream_t stream) {
  const float* x  = (const float*)d_in[0];
  const int*   ei = (const int*)d_in[1];
  const float* c2 = (const float*)d_in[2];
  const float* tf = (const float*)d_in[3];
  const float* a0 = (const float*)d_in[4];
  float* out = (float*)d_out;
  char* ws = (char*)d_ws;
  int*    cnt    = (int*)(ws + OFF_CNT);
  float*  s2xh   = (float*)(ws + OFF_S2X);
  double* stats  = (double*)(ws + OFF_STATS);
  int*    flag   = (int*)(ws + OFF_FLAG);
  int*    nbc    = (int*)(ws + OFF_NBC);
  int*    neigh  = (int*)(ws + OFF_NEIGH);
  int*    buf    = (int*)(ws + OFF_BUF);
  float*  params = (float*)(ws + OFF_PARAMS);
  (void)in_sizes; (void)n_in; (void)out_size; (void)ws_size;

  hipMemsetAsync(ws, 0, MEMSET_LEN, stream);   // zero cnt, stats, flag
  k_scatter<<<N_EDGES / 256, 256, 0, stream>>>(ei, cnt, buf);
  k_selstats<<<SS_BLOCKS, 256, 0, stream>>>(ei, cnt, buf, x, nbc, neigh,
                                            s2xh, stats, flag, tf, c2, a0, params);
  k_main<<<2500, 320, 0, stream>>>(x, tf, c2, nbc, neigh, params, s2xh, out);
}